// Round 11
// baseline (12892.949 us; speedup 1.0000x reference)
//
#include <hip/hip_runtime.h>

// ---------------------------------------------------------------------------
// StructureEncoder — optimized: CSR gather aggregation (no atomics in hot
// path), 128x128 LDS-tiled fp32 GEMM with fused BN+ReLU, packed head GEMM.
// d_out (fp32) doubles as the h buffer; head result staged in ws, then d2d.
// ---------------------------------------------------------------------------

__global__ void k_edetect(const int* __restrict__ ei, int n, int* __restrict__ flag) {
    if (threadIdx.x == 0 && blockIdx.x == 0) {
        int is64 = 1;
        for (int i = 0; i < 64; ++i) {
            if (ei[2 * i + 1] != 0 || (unsigned)ei[2 * i] >= (unsigned)n) { is64 = 0; break; }
        }
        *flag = is64;
    }
}

__global__ __launch_bounds__(256) void deg_count(const int* __restrict__ ei,
                                                 const int* __restrict__ eflag,
                                                 unsigned* __restrict__ deg, int e, int n) {
    int i = blockIdx.x * 256 + threadIdx.x;
    if (i >= e) return;
    int d = (*eflag) ? ei[2 * (size_t)e + 2 * (size_t)i] : ei[(size_t)e + i];
    if ((unsigned)d < (unsigned)n) atomicAdd(&deg[d], 1u);
}

__global__ __launch_bounds__(256) void node_init(const unsigned* __restrict__ deg,
                                                 float* __restrict__ dis,
                                                 unsigned* __restrict__ starts,
                                                 unsigned* __restrict__ cursor,
                                                 unsigned* __restrict__ total, int n) {
    int i = blockIdx.x * 256 + threadIdx.x;
    if (i < n) {
        unsigned d = deg[i];
        dis[i] = rsqrtf((float)d + 1.0f);          // degree with self loop
        unsigned s = atomicAdd(total, d);
        starts[i] = s;
        cursor[i] = s;
    }
}

__global__ __launch_bounds__(256) void csr_fill(const int* __restrict__ ei,
                                                const int* __restrict__ eflag,
                                                unsigned* __restrict__ cursor,
                                                int* __restrict__ csr_src, int e, int n) {
    int i = blockIdx.x * 256 + threadIdx.x;
    if (i >= e) return;
    int s, d;
    if (*eflag) {
        s = ei[2 * (size_t)i];
        d = ei[2 * (size_t)e + 2 * (size_t)i];
    } else {
        s = ei[i];
        d = ei[(size_t)e + i];
    }
    if ((unsigned)s >= (unsigned)n || (unsigned)d >= (unsigned)n) return;
    unsigned slot = atomicAdd(&cursor[d], 1u);
    if (slot < (unsigned)e) csr_src[slot] = s;
}

// ---- aggregation (gather): one 64-lane wave per node, float2 per lane ------
// out[node] = dis[node]*sum_e dis[src]*hW[src] + dis[node]^2*hW[node] + bias

__global__ __launch_bounds__(256) void aggregate(const float* __restrict__ hW,
                                                 const int* __restrict__ csr_src,
                                                 const unsigned* __restrict__ starts,
                                                 const unsigned* __restrict__ deg,
                                                 const float* __restrict__ dis,
                                                 const float* __restrict__ bias,
                                                 float* __restrict__ outh, int n) {
    int node = blockIdx.x * 4 + (threadIdx.x >> 6);
    int lane = threadIdx.x & 63;
    if (node >= n) return;
    unsigned s0 = starts[node], dn = deg[node];
    float ax = 0.f, ay = 0.f;
    for (unsigned j = 0; j < dn; ++j) {
        int   s = csr_src[s0 + j];
        float w = dis[s];
        float2 v = *(const float2*)(hW + (size_t)s * 128 + lane * 2);
        ax = fmaf(v.x, w, ax);
        ay = fmaf(v.y, w, ay);
    }
    float dii = dis[node];
    float2 vs = *(const float2*)(hW + (size_t)node * 128 + lane * 2);
    float rx = fmaf(dii, ax, dii * dii * vs.x) + bias[lane * 2];
    float ry = fmaf(dii, ay, dii * dii * vs.y) + bias[lane * 2 + 1];
    *(float2*)(outh + (size_t)node * 128 + lane * 2) = make_float2(rx, ry);
}

// ---- BatchNorm statistics (coalesced row streaming + block-level atomics) --

__global__ __launch_bounds__(256) void bn_stats(const float* __restrict__ h,
                                                float* __restrict__ sums, int n) {
    int tid = threadIdx.x;
    int c = tid & 127, half = tid >> 7;
    float s = 0.f, s2 = 0.f;
    for (int r = blockIdx.x * 2 + half; r < n; r += gridDim.x * 2) {
        float v = h[(size_t)r * 128 + c];
        s += v;
        s2 = fmaf(v, v, s2);
    }
    __shared__ float sh[256];
    sh[tid] = s;
    __syncthreads();
    if (tid < 128) atomicAdd(&sums[tid], sh[tid] + sh[tid + 128]);
    __syncthreads();
    sh[tid] = s2;
    __syncthreads();
    if (tid < 128) atomicAdd(&sums[128 + tid], sh[tid] + sh[tid + 128]);
}

__global__ void bn_final(const float* __restrict__ sums, const float* __restrict__ g,
                         const float* __restrict__ be, float* __restrict__ bnp, int n) {
    int c = threadIdx.x;                            // 128 threads
    float inv_n = 1.0f / (float)n;
    float mean = sums[c] * inv_n;
    float var  = sums[128 + c] * inv_n - mean * mean;
    float sc   = g[c] * rsqrtf(var + 1e-5f);
    bnp[c]       = sc;
    bnp[128 + c] = be[c] - mean * sc;
}

// ---- head weight packing: Wcat[k][j] = j<64 ? Wmu : Wlv --------------------

__global__ __launch_bounds__(256) void pack_head(const float* __restrict__ Wmu,
                                                 const float* __restrict__ Wlv,
                                                 const float* __restrict__ bmu,
                                                 const float* __restrict__ blv,
                                                 float* __restrict__ Wcat,
                                                 float* __restrict__ bcat) {
    int idx = blockIdx.x * 256 + threadIdx.x;
    if (idx < 16384) {
        int k = idx >> 7, j = idx & 127;
        Wcat[idx] = (j < 64) ? Wmu[k * 64 + j] : Wlv[k * 64 + (j - 64)];
    }
    if (idx < 128) bcat[idx] = (idx < 64) ? bmu[idx] : blv[idx - 64];
}

// ---- tiled fp32 GEMM: C[M,128] = bnrelu(A)[M,128] @ W[128,128] -------------
// 128x128 tile per 256-thread block, 8x8 micro-tile, K chunked by 32.
// BN+ReLU fused on A load (bnp != nullptr). HEAD: +bias, split fp32 store.

template <bool HEAD>
__global__ __launch_bounds__(256) void gemm_tile(const float* __restrict__ A,
                                                 const float* __restrict__ W,
                                                 const float* __restrict__ bnp,
                                                 const float* __restrict__ bias,
                                                 float* __restrict__ C, int nrows) {
    __shared__ float Ast[32][132];   // A^T chunk [k][row]
    __shared__ float Bs[32][128];
    __shared__ float bnsc[128], bnsh[128];

    const int tid = threadIdx.x;
    const int rowbase = blockIdx.x * 128;
    const bool has_bn = (bnp != nullptr);
    if (has_bn && tid < 128) {
        bnsc[tid] = bnp[tid];
        bnsh[tid] = bnp[128 + tid];
    }
    __syncthreads();

    const int tx = tid & 15, ty = tid >> 4;
    float acc[8][8];
#pragma unroll
    for (int i = 0; i < 8; ++i)
#pragma unroll
        for (int j = 0; j < 8; ++j) acc[i][j] = 0.f;

#pragma unroll
    for (int k0 = 0; k0 < 128; k0 += 32) {
#pragma unroll
        for (int p = 0; p < 4; ++p) {
            int r  = (tid >> 3) + p * 32;
            int kc = (tid & 7) * 4;
            int gr = rowbase + r;
            float4 v = make_float4(0.f, 0.f, 0.f, 0.f);
            if (gr < nrows) v = *(const float4*)(A + (size_t)gr * 128 + k0 + kc);
            if (has_bn) {
                v.x = fmaxf(0.f, fmaf(v.x, bnsc[k0 + kc + 0], bnsh[k0 + kc + 0]));
                v.y = fmaxf(0.f, fmaf(v.y, bnsc[k0 + kc + 1], bnsh[k0 + kc + 1]));
                v.z = fmaxf(0.f, fmaf(v.z, bnsc[k0 + kc + 2], bnsh[k0 + kc + 2]));
                v.w = fmaxf(0.f, fmaf(v.w, bnsc[k0 + kc + 3], bnsh[k0 + kc + 3]));
            }
            Ast[kc + 0][r] = v.x;
            Ast[kc + 1][r] = v.y;
            Ast[kc + 2][r] = v.z;
            Ast[kc + 3][r] = v.w;
        }
#pragma unroll
        for (int p = 0; p < 4; ++p) {
            int kr  = (tid >> 5) + p * 8;
            int col = (tid & 31) * 4;
            *(float4*)&Bs[kr][col] = *(const float4*)(W + (size_t)(k0 + kr) * 128 + col);
        }
        __syncthreads();

#pragma unroll
        for (int kk = 0; kk < 32; ++kk) {
            float4 a0 = *(const float4*)&Ast[kk][ty * 4];
            float4 a1 = *(const float4*)&Ast[kk][64 + ty * 4];
            float4 b0 = *(const float4*)&Bs[kk][tx * 4];
            float4 b1 = *(const float4*)&Bs[kk][64 + tx * 4];
            float av[8] = {a0.x, a0.y, a0.z, a0.w, a1.x, a1.y, a1.z, a1.w};
            float bv[8] = {b0.x, b0.y, b0.z, b0.w, b1.x, b1.y, b1.z, b1.w};
#pragma unroll
            for (int i = 0; i < 8; ++i)
#pragma unroll
                for (int j = 0; j < 8; ++j)
                    acc[i][j] = fmaf(av[i], bv[j], acc[i][j]);
        }
        __syncthreads();
    }

    if (!HEAD) {
#pragma unroll
        for (int i = 0; i < 8; ++i) {
            int r = rowbase + (i < 4 ? ty * 4 + i : 64 + ty * 4 + (i - 4));
            if (r < nrows) {
                *(float4*)(C + (size_t)r * 128 + tx * 4) =
                    make_float4(acc[i][0], acc[i][1], acc[i][2], acc[i][3]);
                *(float4*)(C + (size_t)r * 128 + 64 + tx * 4) =
                    make_float4(acc[i][4], acc[i][5], acc[i][6], acc[i][7]);
            }
        }
    } else {
        float* mu = C;
        float* lv = C + (size_t)nrows * 64;
        float4 bb0 = *(const float4*)&bias[tx * 4];
        float4 bb1 = *(const float4*)&bias[64 + tx * 4];
#pragma unroll
        for (int i = 0; i < 8; ++i) {
            int r = rowbase + (i < 4 ? ty * 4 + i : 64 + ty * 4 + (i - 4));
            if (r < nrows) {
                *(float4*)(mu + (size_t)r * 64 + tx * 4) =
                    make_float4(acc[i][0] + bb0.x, acc[i][1] + bb0.y,
                                acc[i][2] + bb0.z, acc[i][3] + bb0.w);
                *(float4*)(lv + (size_t)r * 64 + tx * 4) =
                    make_float4(acc[i][4] + bb1.x, acc[i][5] + bb1.y,
                                acc[i][6] + bb1.z, acc[i][7] + bb1.w);
            }
        }
    }
}

// ---------------------------------------------------------------------------

extern "C" void kernel_launch(void* const* d_in, const int* in_sizes, int n_in,
                              void* d_out, int out_size, void* d_ws, size_t ws_size,
                              hipStream_t stream) {
    const float* x   = (const float*)d_in[0];
    const int*   ei  = (const int*)d_in[1];
    const float* W1  = (const float*)d_in[2];
    const float* b1  = (const float*)d_in[3];
    const float* g1  = (const float*)d_in[4];
    const float* be1 = (const float*)d_in[5];
    const float* W2  = (const float*)d_in[6];
    const float* b2  = (const float*)d_in[7];
    const float* g2  = (const float*)d_in[8];
    const float* be2 = (const float*)d_in[9];
    const float* Wmu = (const float*)d_in[10];
    const float* bmu = (const float*)d_in[11];
    const float* Wlv = (const float*)d_in[12];
    const float* blv = (const float*)d_in[13];

    const int n = in_sizes[0] / 128;   // 100000
    const int e = in_sizes[1] / 2;     // 1600000

    const size_t nbytes = (size_t)n * 128 * 4;
    char* ws = (char*)d_ws;
    size_t off = 0;
    auto alloc = [&](size_t bytes) {
        void* p = ws + off;
        off = (off + bytes + 255) & ~(size_t)255;
        return p;
    };
    float*    bufW    = (float*)alloc(nbytes);          // hW / head result
    int*      csr_src = (int*)alloc((size_t)e * 4);
    unsigned* deg     = (unsigned*)alloc((size_t)n * 4);
    float*    dis     = (float*)alloc((size_t)n * 4);
    unsigned* starts  = (unsigned*)alloc((size_t)n * 4);
    unsigned* cursor  = (unsigned*)alloc((size_t)n * 4);
    unsigned* total   = (unsigned*)alloc(256);
    int*      eflag   = (int*)alloc(256);
    float*    sums    = (float*)alloc(256 * 4);
    float*    bnp     = (float*)alloc(256 * 4);
    float*    Wcat    = (float*)alloc(16384 * 4);
    float*    bcat    = (float*)alloc(128 * 4);
    // total ws ~60 MB

    float* H = (float*)d_out;          // h buffer lives in d_out (fp32, n*128)

    const int eb = (e + 255) / 256;
    const int nb = (n + 255) / 256;
    const int gb = (n + 127) / 128;
    const int ab = (n + 3) / 4;

    // graph preprocessing (CSR by dst)
    hipMemsetAsync(deg, 0, (size_t)n * 4, stream);
    hipMemsetAsync(total, 0, 4, stream);
    k_edetect<<<1, 64, 0, stream>>>(ei, n, eflag);
    deg_count<<<eb, 256, 0, stream>>>(ei, eflag, deg, e, n);
    node_init<<<nb, 256, 0, stream>>>(deg, dis, starts, cursor, total, n);
    csr_fill<<<eb, 256, 0, stream>>>(ei, eflag, cursor, csr_src, e, n);

    // layer 1: hW1 = x@W1 -> bufW ; h1 = agg+b1 -> H ; bn1
    gemm_tile<false><<<gb, 256, 0, stream>>>(x, W1, nullptr, nullptr, bufW, n);
    aggregate<<<ab, 256, 0, stream>>>(bufW, csr_src, starts, deg, dis, b1, H, n);
    hipMemsetAsync(sums, 0, 1024, stream);
    bn_stats<<<512, 256, 0, stream>>>(H, sums, n);
    bn_final<<<1, 128, 0, stream>>>(sums, g1, be1, bnp, n);

    // layer 2: hW2 = bnrelu(h1)@W2 -> bufW ; h2 = agg+b2 -> H ; bn2
    gemm_tile<false><<<gb, 256, 0, stream>>>(H, W2, bnp, nullptr, bufW, n);
    aggregate<<<ab, 256, 0, stream>>>(bufW, csr_src, starts, deg, dis, b2, H, n);
    hipMemsetAsync(sums, 0, 1024, stream);
    bn_stats<<<512, 256, 0, stream>>>(H, sums, n);
    bn_final<<<1, 128, 0, stream>>>(sums, g2, be2, bnp, n);

    // heads: bnrelu(h2)@[Wmu|Wlv]+[bmu|blv] -> bufW (mu||lv), then d2d to d_out
    pack_head<<<64, 256, 0, stream>>>(Wmu, Wlv, bmu, blv, Wcat, bcat);
    gemm_tile<true><<<gb, 256, 0, stream>>>(H, Wcat, bnp, bcat, bufW, n);
    hipMemcpyAsync(d_out, bufW, nbytes, hipMemcpyDeviceToDevice, stream);
}

// Round 12
// 817.115 us; speedup vs baseline: 15.7786x; 15.7786x over previous
//
#include <hip/hip_runtime.h>

// ---------------------------------------------------------------------------
// StructureEncoder — CSR gather aggregation + 64x64-tile fp32 GEMM (4x4
// micro-tile, 16 acc regs; the round-11 8x8 variant spilled at VGPR=256 and
// fetched 4.8 GB/dispatch of scratch traffic). BN+ReLU fused into GEMM A-load.
// d_out (fp32) doubles as the h buffer; head result staged in ws, then d2d.
// ---------------------------------------------------------------------------

__global__ void k_edetect(const int* __restrict__ ei, int n, int* __restrict__ flag) {
    if (threadIdx.x == 0 && blockIdx.x == 0) {
        int is64 = 1;
        for (int i = 0; i < 64; ++i) {
            if (ei[2 * i + 1] != 0 || (unsigned)ei[2 * i] >= (unsigned)n) { is64 = 0; break; }
        }
        *flag = is64;
    }
}

__global__ __launch_bounds__(256) void deg_count(const int* __restrict__ ei,
                                                 const int* __restrict__ eflag,
                                                 unsigned* __restrict__ deg, int e, int n) {
    int i = blockIdx.x * 256 + threadIdx.x;
    if (i >= e) return;
    int d = (*eflag) ? ei[2 * (size_t)e + 2 * (size_t)i] : ei[(size_t)e + i];
    if ((unsigned)d < (unsigned)n) atomicAdd(&deg[d], 1u);
}

__global__ __launch_bounds__(256) void node_init(const unsigned* __restrict__ deg,
                                                 float* __restrict__ dis,
                                                 unsigned* __restrict__ starts,
                                                 unsigned* __restrict__ cursor,
                                                 unsigned* __restrict__ total, int n) {
    int i = blockIdx.x * 256 + threadIdx.x;
    if (i < n) {
        unsigned d = deg[i];
        dis[i] = rsqrtf((float)d + 1.0f);          // degree with self loop
        unsigned s = atomicAdd(total, d);
        starts[i] = s;
        cursor[i] = s;
    }
}

__global__ __launch_bounds__(256) void csr_fill(const int* __restrict__ ei,
                                                const int* __restrict__ eflag,
                                                unsigned* __restrict__ cursor,
                                                int* __restrict__ csr_src, int e, int n) {
    int i = blockIdx.x * 256 + threadIdx.x;
    if (i >= e) return;
    int s, d;
    if (*eflag) {
        s = ei[2 * (size_t)i];
        d = ei[2 * (size_t)e + 2 * (size_t)i];
    } else {
        s = ei[i];
        d = ei[(size_t)e + i];
    }
    if ((unsigned)s >= (unsigned)n || (unsigned)d >= (unsigned)n) return;
    unsigned slot = atomicAdd(&cursor[d], 1u);
    if (slot < (unsigned)e) csr_src[slot] = s;
}

// ---- aggregation (gather): one 64-lane wave per node, float2 per lane ------
// out[node] = dis[node]*sum_e dis[src]*hW[src] + dis[node]^2*hW[node] + bias

__global__ __launch_bounds__(256) void aggregate(const float* __restrict__ hW,
                                                 const int* __restrict__ csr_src,
                                                 const unsigned* __restrict__ starts,
                                                 const unsigned* __restrict__ deg,
                                                 const float* __restrict__ dis,
                                                 const float* __restrict__ bias,
                                                 float* __restrict__ outh, int n) {
    int node = blockIdx.x * 4 + (threadIdx.x >> 6);
    int lane = threadIdx.x & 63;
    if (node >= n) return;
    unsigned s0 = starts[node], dn = deg[node];
    float ax = 0.f, ay = 0.f;
    for (unsigned j = 0; j < dn; ++j) {
        int   s = csr_src[s0 + j];
        float w = dis[s];
        float2 v = *(const float2*)(hW + (size_t)s * 128 + lane * 2);
        ax = fmaf(v.x, w, ax);
        ay = fmaf(v.y, w, ay);
    }
    float dii = dis[node];
    float2 vs = *(const float2*)(hW + (size_t)node * 128 + lane * 2);
    float rx = fmaf(dii, ax, dii * dii * vs.x) + bias[lane * 2];
    float ry = fmaf(dii, ay, dii * dii * vs.y) + bias[lane * 2 + 1];
    *(float2*)(outh + (size_t)node * 128 + lane * 2) = make_float2(rx, ry);
}

// ---- BatchNorm statistics --------------------------------------------------

__global__ __launch_bounds__(256) void bn_stats(const float* __restrict__ h,
                                                float* __restrict__ sums, int n) {
    int tid = threadIdx.x;
    int c = tid & 127, half = tid >> 7;
    float s = 0.f, s2 = 0.f;
    for (int r = blockIdx.x * 2 + half; r < n; r += gridDim.x * 2) {
        float v = h[(size_t)r * 128 + c];
        s += v;
        s2 = fmaf(v, v, s2);
    }
    __shared__ float sh[256];
    sh[tid] = s;
    __syncthreads();
    if (tid < 128) atomicAdd(&sums[tid], sh[tid] + sh[tid + 128]);
    __syncthreads();
    sh[tid] = s2;
    __syncthreads();
    if (tid < 128) atomicAdd(&sums[128 + tid], sh[tid] + sh[tid + 128]);
}

__global__ void bn_final(const float* __restrict__ sums, const float* __restrict__ g,
                         const float* __restrict__ be, float* __restrict__ bnp, int n) {
    int c = threadIdx.x;                            // 128 threads
    float inv_n = 1.0f / (float)n;
    float mean = sums[c] * inv_n;
    float var  = sums[128 + c] * inv_n - mean * mean;
    float sc   = g[c] * rsqrtf(var + 1e-5f);
    bnp[c]       = sc;
    bnp[128 + c] = be[c] - mean * sc;
}

// ---- head weight packing: Wcat[k][j] = j<64 ? Wmu : Wlv --------------------

__global__ __launch_bounds__(256) void pack_head(const float* __restrict__ Wmu,
                                                 const float* __restrict__ Wlv,
                                                 const float* __restrict__ bmu,
                                                 const float* __restrict__ blv,
                                                 float* __restrict__ Wcat,
                                                 float* __restrict__ bcat) {
    int idx = blockIdx.x * 256 + threadIdx.x;
    if (idx < 16384) {
        int k = idx >> 7, j = idx & 127;
        Wcat[idx] = (j < 64) ? Wmu[k * 64 + j] : Wlv[k * 64 + (j - 64)];
    }
    if (idx < 128) bcat[idx] = (idx < 64) ? bmu[idx] : blv[idx - 64];
}

// ---- tiled fp32 GEMM: C[M,128] = bnrelu(A)[M,128] @ W[128,128] -------------
// 64x64 tile per 256-thread block (blockIdx.y = column tile), 4x4 micro-tile,
// K chunked by 32. 16 acc regs -> no spills. BN+ReLU fused on A load.
// HEAD: +bias; col-tile 0 -> mu block, col-tile 1 -> logvar block.

template <bool HEAD>
__global__ __launch_bounds__(256, 4) void gemm64(const float* __restrict__ A,
                                                 const float* __restrict__ W,
                                                 const float* __restrict__ bnp,
                                                 const float* __restrict__ bias,
                                                 float* __restrict__ C, int nrows) {
    __shared__ float Ast[32][68];   // A^T chunk [k][row], pad 68 (b128-aligned)
    __shared__ float Bs[32][68];
    __shared__ float bnsc[128], bnsh[128];

    const int tid = threadIdx.x;
    const int rowbase = blockIdx.x * 64;
    const int colbase = blockIdx.y * 64;
    const bool has_bn = (bnp != nullptr);
    if (has_bn && tid < 128) {
        bnsc[tid] = bnp[tid];
        bnsh[tid] = bnp[128 + tid];
    }
    __syncthreads();

    const int tx = tid & 15, ty = tid >> 4;
    float acc[4][4];
#pragma unroll
    for (int i = 0; i < 4; ++i)
#pragma unroll
        for (int j = 0; j < 4; ++j) acc[i][j] = 0.f;

    for (int k0 = 0; k0 < 128; k0 += 32) {
        // stage A tile (64 rows x 32 k), transposed into LDS
#pragma unroll
        for (int p = 0; p < 2; ++p) {
            int idx = tid + p * 256;
            int r   = idx >> 3;          // 0..63
            int kc  = (idx & 7) * 4;     // 0..28
            int gr  = rowbase + r;
            float4 v = make_float4(0.f, 0.f, 0.f, 0.f);
            if (gr < nrows) v = *(const float4*)(A + (size_t)gr * 128 + k0 + kc);
            if (has_bn) {
                v.x = fmaxf(0.f, fmaf(v.x, bnsc[k0 + kc + 0], bnsh[k0 + kc + 0]));
                v.y = fmaxf(0.f, fmaf(v.y, bnsc[k0 + kc + 1], bnsh[k0 + kc + 1]));
                v.z = fmaxf(0.f, fmaf(v.z, bnsc[k0 + kc + 2], bnsh[k0 + kc + 2]));
                v.w = fmaxf(0.f, fmaf(v.w, bnsc[k0 + kc + 3], bnsh[k0 + kc + 3]));
            }
            Ast[kc + 0][r] = v.x;
            Ast[kc + 1][r] = v.y;
            Ast[kc + 2][r] = v.z;
            Ast[kc + 3][r] = v.w;
        }
        // stage W tile (32 k x 64 cols)
#pragma unroll
        for (int p = 0; p < 2; ++p) {
            int idx = tid + p * 256;
            int kr  = idx >> 4;          // 0..31
            int c4  = (idx & 15) * 4;    // 0..60
            *(float4*)&Bs[kr][c4] = *(const float4*)(W + (size_t)(k0 + kr) * 128 + colbase + c4);
        }
        __syncthreads();

#pragma unroll
        for (int kk = 0; kk < 32; ++kk) {
            float4 a = *(const float4*)&Ast[kk][ty * 4];
            float4 b = *(const float4*)&Bs[kk][tx * 4];
            float av[4] = {a.x, a.y, a.z, a.w};
            float bv[4] = {b.x, b.y, b.z, b.w};
#pragma unroll
            for (int i = 0; i < 4; ++i)
#pragma unroll
                for (int j = 0; j < 4; ++j)
                    acc[i][j] = fmaf(av[i], bv[j], acc[i][j]);
        }
        __syncthreads();
    }

    if (!HEAD) {
#pragma unroll
        for (int i = 0; i < 4; ++i) {
            int r = rowbase + ty * 4 + i;
            if (r < nrows) {
                *(float4*)(C + (size_t)r * 128 + colbase + tx * 4) =
                    make_float4(acc[i][0], acc[i][1], acc[i][2], acc[i][3]);
            }
        }
    } else {
        float* dst = C + (blockIdx.y ? (size_t)nrows * 64 : 0);   // mu | logvar
        float4 bb = *(const float4*)&bias[colbase + tx * 4];
#pragma unroll
        for (int i = 0; i < 4; ++i) {
            int r = rowbase + ty * 4 + i;
            if (r < nrows) {
                *(float4*)(dst + (size_t)r * 64 + tx * 4) =
                    make_float4(acc[i][0] + bb.x, acc[i][1] + bb.y,
                                acc[i][2] + bb.z, acc[i][3] + bb.w);
            }
        }
    }
}

// ---------------------------------------------------------------------------

extern "C" void kernel_launch(void* const* d_in, const int* in_sizes, int n_in,
                              void* d_out, int out_size, void* d_ws, size_t ws_size,
                              hipStream_t stream) {
    const float* x   = (const float*)d_in[0];
    const int*   ei  = (const int*)d_in[1];
    const float* W1  = (const float*)d_in[2];
    const float* b1  = (const float*)d_in[3];
    const float* g1  = (const float*)d_in[4];
    const float* be1 = (const float*)d_in[5];
    const float* W2  = (const float*)d_in[6];
    const float* b2  = (const float*)d_in[7];
    const float* g2  = (const float*)d_in[8];
    const float* be2 = (const float*)d_in[9];
    const float* Wmu = (const float*)d_in[10];
    const float* bmu = (const float*)d_in[11];
    const float* Wlv = (const float*)d_in[12];
    const float* blv = (const float*)d_in[13];

    const int n = in_sizes[0] / 128;   // 100000
    const int e = in_sizes[1] / 2;     // 1600000

    const size_t nbytes = (size_t)n * 128 * 4;
    char* ws = (char*)d_ws;
    size_t off = 0;
    auto alloc = [&](size_t bytes) {
        void* p = ws + off;
        off = (off + bytes + 255) & ~(size_t)255;
        return p;
    };
    float*    bufW    = (float*)alloc(nbytes);          // hW / head result
    int*      csr_src = (int*)alloc((size_t)e * 4);
    unsigned* deg     = (unsigned*)alloc((size_t)n * 4);
    float*    dis     = (float*)alloc((size_t)n * 4);
    unsigned* starts  = (unsigned*)alloc((size_t)n * 4);
    unsigned* cursor  = (unsigned*)alloc((size_t)n * 4);
    unsigned* total   = (unsigned*)alloc(256);
    int*      eflag   = (int*)alloc(256);
    float*    sums    = (float*)alloc(256 * 4);
    float*    bnp     = (float*)alloc(256 * 4);
    float*    Wcat    = (float*)alloc(16384 * 4);
    float*    bcat    = (float*)alloc(128 * 4);

    float* H = (float*)d_out;          // h buffer lives in d_out (fp32, n*128)

    const int eb = (e + 255) / 256;
    const int nb = (n + 255) / 256;
    const int ab = (n + 3) / 4;
    const dim3 gg((n + 63) / 64, 2);   // 64-row tiles x 2 col-tiles

    // graph preprocessing (CSR by dst)
    hipMemsetAsync(deg, 0, (size_t)n * 4, stream);
    hipMemsetAsync(total, 0, 4, stream);
    k_edetect<<<1, 64, 0, stream>>>(ei, n, eflag);
    deg_count<<<eb, 256, 0, stream>>>(ei, eflag, deg, e, n);
    node_init<<<nb, 256, 0, stream>>>(deg, dis, starts, cursor, total, n);
    csr_fill<<<eb, 256, 0, stream>>>(ei, eflag, cursor, csr_src, e, n);

    // layer 1: hW1 = x@W1 -> bufW ; h1 = agg+b1 -> H ; bn1
    gemm64<false><<<gg, 256, 0, stream>>>(x, W1, nullptr, nullptr, bufW, n);
    aggregate<<<ab, 256, 0, stream>>>(bufW, csr_src, starts, deg, dis, b1, H, n);
    hipMemsetAsync(sums, 0, 1024, stream);
    bn_stats<<<512, 256, 0, stream>>>(H, sums, n);
    bn_final<<<1, 128, 0, stream>>>(sums, g1, be1, bnp, n);

    // layer 2: hW2 = bnrelu(h1)@W2 -> bufW ; h2 = agg+b2 -> H ; bn2
    gemm64<false><<<gg, 256, 0, stream>>>(H, W2, bnp, nullptr, bufW, n);
    aggregate<<<ab, 256, 0, stream>>>(bufW, csr_src, starts, deg, dis, b2, H, n);
    hipMemsetAsync(sums, 0, 1024, stream);
    bn_stats<<<512, 256, 0, stream>>>(H, sums, n);
    bn_final<<<1, 128, 0, stream>>>(sums, g2, be2, bnp, n);

    // heads: bnrelu(h2)@[Wmu|Wlv]+[bmu|blv] -> bufW (mu||lv), then d2d to d_out
    pack_head<<<64, 256, 0, stream>>>(Wmu, Wlv, bmu, blv, Wcat, bcat);
    gemm64<true><<<gg, 256, 0, stream>>>(H, Wcat, bnp, bcat, bufW, n);
    hipMemcpyAsync(d_out, bufW, nbytes, hipMemcpyDeviceToDevice, stream);
}

// Round 13
// 787.439 us; speedup vs baseline: 16.3733x; 1.0377x over previous
//
#include <hip/hip_runtime.h>

// ---------------------------------------------------------------------------
// StructureEncoder — CSR gather aggregation over *bf16* hW (halves gather
// bytes; 25.6MB fits aggregate L2), 64x128-tile fp32 GEMM (4x8 micro-tile,
// 32 acc regs), BN+ReLU fused into GEMM A-load, head GEMM writes d_out
// directly (no d2d). Intermediate H stays fp32 in ws.
// ---------------------------------------------------------------------------

__device__ inline unsigned short f2bf(float f) {
    unsigned u = __float_as_uint(f);
    unsigned r = u + 0x7FFFu + ((u >> 16) & 1u);   // RNE
    return (unsigned short)(r >> 16);
}
__device__ inline float bf2f(unsigned u16) {
    return __uint_as_float(u16 << 16);
}

__global__ void k_edetect(const int* __restrict__ ei, int n, int* __restrict__ flag) {
    if (threadIdx.x == 0 && blockIdx.x == 0) {
        int is64 = 1;
        for (int i = 0; i < 64; ++i) {
            if (ei[2 * i + 1] != 0 || (unsigned)ei[2 * i] >= (unsigned)n) { is64 = 0; break; }
        }
        *flag = is64;
    }
}

__global__ __launch_bounds__(256) void deg_count(const int* __restrict__ ei,
                                                 const int* __restrict__ eflag,
                                                 unsigned* __restrict__ deg, int e, int n) {
    int i = blockIdx.x * 256 + threadIdx.x;
    if (i >= e) return;
    int d = (*eflag) ? ei[2 * (size_t)e + 2 * (size_t)i] : ei[(size_t)e + i];
    if ((unsigned)d < (unsigned)n) atomicAdd(&deg[d], 1u);
}

__global__ __launch_bounds__(256) void node_init(const unsigned* __restrict__ deg,
                                                 float* __restrict__ dis,
                                                 unsigned* __restrict__ starts,
                                                 unsigned* __restrict__ cursor,
                                                 unsigned* __restrict__ total, int n) {
    int i = blockIdx.x * 256 + threadIdx.x;
    if (i < n) {
        unsigned d = deg[i];
        dis[i] = rsqrtf((float)d + 1.0f);          // degree with self loop
        unsigned s = atomicAdd(total, d);
        starts[i] = s;
        cursor[i] = s;
    }
}

__global__ __launch_bounds__(256) void csr_fill(const int* __restrict__ ei,
                                                const int* __restrict__ eflag,
                                                unsigned* __restrict__ cursor,
                                                int* __restrict__ csr_src, int e, int n) {
    int i = blockIdx.x * 256 + threadIdx.x;
    if (i >= e) return;
    int s, d;
    if (*eflag) {
        s = ei[2 * (size_t)i];
        d = ei[2 * (size_t)e + 2 * (size_t)i];
    } else {
        s = ei[i];
        d = ei[(size_t)e + i];
    }
    if ((unsigned)s >= (unsigned)n || (unsigned)d >= (unsigned)n) return;
    unsigned slot = atomicAdd(&cursor[d], 1u);
    if (slot < (unsigned)e) csr_src[slot] = s;
}

// ---- aggregation (gather, bf16 hW): one 64-lane wave per node --------------
// out[node] = dis[node]*sum_e dis[src]*hW[src] + dis[node]^2*hW[node] + bias

__global__ __launch_bounds__(256) void aggregate(const unsigned* __restrict__ hWb,  // bf16x2
                                                 const int* __restrict__ csr_src,
                                                 const unsigned* __restrict__ starts,
                                                 const unsigned* __restrict__ deg,
                                                 const float* __restrict__ dis,
                                                 const float* __restrict__ bias,
                                                 float* __restrict__ outh, int n) {
    int node = blockIdx.x * 4 + (threadIdx.x >> 6);
    int lane = threadIdx.x & 63;
    if (node >= n) return;
    unsigned s0 = starts[node], dn = deg[node];
    float ax = 0.f, ay = 0.f;
    for (unsigned j = 0; j < dn; ++j) {
        int      s = csr_src[s0 + j];
        float    w = dis[s];
        unsigned v = hWb[(size_t)s * 64 + lane];
        ax = fmaf(bf2f(v & 0xFFFFu), w, ax);
        ay = fmaf(bf2f(v >> 16), w, ay);
    }
    float dii = dis[node];
    unsigned vs = hWb[(size_t)node * 64 + lane];
    float rx = fmaf(dii, ax, dii * dii * bf2f(vs & 0xFFFFu)) + bias[lane * 2];
    float ry = fmaf(dii, ay, dii * dii * bf2f(vs >> 16)) + bias[lane * 2 + 1];
    *(float2*)(outh + (size_t)node * 128 + lane * 2) = make_float2(rx, ry);
}

// ---- BatchNorm statistics --------------------------------------------------

__global__ __launch_bounds__(256) void bn_stats(const float* __restrict__ h,
                                                float* __restrict__ sums, int n) {
    int tid = threadIdx.x;
    int c = tid & 127, half = tid >> 7;
    float s = 0.f, s2 = 0.f;
    for (int r = blockIdx.x * 2 + half; r < n; r += gridDim.x * 2) {
        float v = h[(size_t)r * 128 + c];
        s += v;
        s2 = fmaf(v, v, s2);
    }
    __shared__ float sh[256];
    sh[tid] = s;
    __syncthreads();
    if (tid < 128) atomicAdd(&sums[tid], sh[tid] + sh[tid + 128]);
    __syncthreads();
    sh[tid] = s2;
    __syncthreads();
    if (tid < 128) atomicAdd(&sums[128 + tid], sh[tid] + sh[tid + 128]);
}

__global__ void bn_final(const float* __restrict__ sums, const float* __restrict__ g,
                         const float* __restrict__ be, float* __restrict__ bnp, int n) {
    int c = threadIdx.x;                            // 128 threads
    float inv_n = 1.0f / (float)n;
    float mean = sums[c] * inv_n;
    float var  = sums[128 + c] * inv_n - mean * mean;
    float sc   = g[c] * rsqrtf(var + 1e-5f);
    bnp[c]       = sc;
    bnp[128 + c] = be[c] - mean * sc;
}

// ---- head weight packing: Wcat[k][j] = j<64 ? Wmu : Wlv --------------------

__global__ __launch_bounds__(256) void pack_head(const float* __restrict__ Wmu,
                                                 const float* __restrict__ Wlv,
                                                 const float* __restrict__ bmu,
                                                 const float* __restrict__ blv,
                                                 float* __restrict__ Wcat,
                                                 float* __restrict__ bcat) {
    int idx = blockIdx.x * 256 + threadIdx.x;
    if (idx < 16384) {
        int k = idx >> 7, j = idx & 127;
        Wcat[idx] = (j < 64) ? Wmu[k * 64 + j] : Wlv[k * 64 + (j - 64)];
    }
    if (idx < 128) bcat[idx] = (idx < 64) ? bmu[idx] : blv[idx - 64];
}

// ---- tiled fp32 GEMM: C[M,128] = bnrelu(A)[M,128] @ W[128,128] -------------
// 64 rows x 128 cols per 256-thread block, 4x8 micro-tile (32 acc regs),
// K chunked by 32. BN+ReLU fused on A load. Output: bf16-packed (hW) or
// fp32 mu|lv split with bias (HEAD, direct to d_out).

template <bool HEAD>
__global__ __launch_bounds__(256, 3) void gemm64(const float* __restrict__ A,
                                                 const float* __restrict__ W,
                                                 const float* __restrict__ bnp,
                                                 const float* __restrict__ bias,
                                                 void* __restrict__ Cv, int nrows) {
    __shared__ float Ast[32][68];    // A^T chunk [k][row]
    __shared__ float Bs[32][132];    // W chunk [k][col] full 128 width
    __shared__ float bnsc[128], bnsh[128];

    const int tid = threadIdx.x;
    const int rowbase = blockIdx.x * 64;
    const bool has_bn = (bnp != nullptr);
    if (has_bn && tid < 128) {
        bnsc[tid] = bnp[tid];
        bnsh[tid] = bnp[128 + tid];
    }
    __syncthreads();

    const int tx = tid & 15, ty = tid >> 4;    // tx: col-group (8 cols), ty: row-group (4 rows)
    float acc[4][8];
#pragma unroll
    for (int i = 0; i < 4; ++i)
#pragma unroll
        for (int j = 0; j < 8; ++j) acc[i][j] = 0.f;

    for (int k0 = 0; k0 < 128; k0 += 32) {
        // stage A tile (64 rows x 32 k), transposed, BN+ReLU fused
#pragma unroll
        for (int p = 0; p < 2; ++p) {
            int idx = tid + p * 256;
            int r   = idx >> 3;
            int kc  = (idx & 7) * 4;
            int gr  = rowbase + r;
            float4 v = make_float4(0.f, 0.f, 0.f, 0.f);
            if (gr < nrows) v = *(const float4*)(A + (size_t)gr * 128 + k0 + kc);
            if (has_bn) {
                v.x = fmaxf(0.f, fmaf(v.x, bnsc[k0 + kc + 0], bnsh[k0 + kc + 0]));
                v.y = fmaxf(0.f, fmaf(v.y, bnsc[k0 + kc + 1], bnsh[k0 + kc + 1]));
                v.z = fmaxf(0.f, fmaf(v.z, bnsc[k0 + kc + 2], bnsh[k0 + kc + 2]));
                v.w = fmaxf(0.f, fmaf(v.w, bnsc[k0 + kc + 3], bnsh[k0 + kc + 3]));
            }
            Ast[kc + 0][r] = v.x;
            Ast[kc + 1][r] = v.y;
            Ast[kc + 2][r] = v.z;
            Ast[kc + 3][r] = v.w;
        }
        // stage W tile (32 k x 128 cols)
#pragma unroll
        for (int p = 0; p < 4; ++p) {
            int idx = tid + p * 256;
            int kr  = idx >> 5;
            int c4  = (idx & 31) * 4;
            *(float4*)&Bs[kr][c4] = *(const float4*)(W + (size_t)(k0 + kr) * 128 + c4);
        }
        __syncthreads();

#pragma unroll
        for (int kk = 0; kk < 32; ++kk) {
            float4 a  = *(const float4*)&Ast[kk][ty * 4];
            float4 b0 = *(const float4*)&Bs[kk][tx * 8];
            float4 b1 = *(const float4*)&Bs[kk][tx * 8 + 4];
            float av[4] = {a.x, a.y, a.z, a.w};
            float bv[8] = {b0.x, b0.y, b0.z, b0.w, b1.x, b1.y, b1.z, b1.w};
#pragma unroll
            for (int i = 0; i < 4; ++i)
#pragma unroll
                for (int j = 0; j < 8; ++j)
                    acc[i][j] = fmaf(av[i], bv[j], acc[i][j]);
        }
        __syncthreads();
    }

    if (!HEAD) {
        // bf16-packed store: row r, cols tx*8 .. tx*8+7 -> 4 uints (16B)
        unsigned* C = (unsigned*)Cv;
#pragma unroll
        for (int i = 0; i < 4; ++i) {
            int r = rowbase + ty * 4 + i;
            if (r < nrows) {
                uint4 o;
                o.x = (unsigned)f2bf(acc[i][0]) | ((unsigned)f2bf(acc[i][1]) << 16);
                o.y = (unsigned)f2bf(acc[i][2]) | ((unsigned)f2bf(acc[i][3]) << 16);
                o.z = (unsigned)f2bf(acc[i][4]) | ((unsigned)f2bf(acc[i][5]) << 16);
                o.w = (unsigned)f2bf(acc[i][6]) | ((unsigned)f2bf(acc[i][7]) << 16);
                *(uint4*)(C + (size_t)r * 64 + tx * 4) = o;
            }
        }
    } else {
        // fp32 split store: cols 0-63 -> mu, 64-127 -> logvar (each thread's
        // 8 cols lie entirely in one half)
        float* out = (float*)Cv;
        float* dst = (tx < 8) ? out : out + (size_t)nrows * 64;
        int    c0  = (tx < 8) ? tx * 8 : (tx - 8) * 8;
        float4 bb0 = *(const float4*)&bias[tx * 8];
        float4 bb1 = *(const float4*)&bias[tx * 8 + 4];
#pragma unroll
        for (int i = 0; i < 4; ++i) {
            int r = rowbase + ty * 4 + i;
            if (r < nrows) {
                *(float4*)(dst + (size_t)r * 64 + c0) =
                    make_float4(acc[i][0] + bb0.x, acc[i][1] + bb0.y,
                                acc[i][2] + bb0.z, acc[i][3] + bb0.w);
                *(float4*)(dst + (size_t)r * 64 + c0 + 4) =
                    make_float4(acc[i][4] + bb1.x, acc[i][5] + bb1.y,
                                acc[i][6] + bb1.z, acc[i][7] + bb1.w);
            }
        }
    }
}

// ---------------------------------------------------------------------------

extern "C" void kernel_launch(void* const* d_in, const int* in_sizes, int n_in,
                              void* d_out, int out_size, void* d_ws, size_t ws_size,
                              hipStream_t stream) {
    const float* x   = (const float*)d_in[0];
    const int*   ei  = (const int*)d_in[1];
    const float* W1  = (const float*)d_in[2];
    const float* b1  = (const float*)d_in[3];
    const float* g1  = (const float*)d_in[4];
    const float* be1 = (const float*)d_in[5];
    const float* W2  = (const float*)d_in[6];
    const float* b2  = (const float*)d_in[7];
    const float* g2  = (const float*)d_in[8];
    const float* be2 = (const float*)d_in[9];
    const float* Wmu = (const float*)d_in[10];
    const float* bmu = (const float*)d_in[11];
    const float* Wlv = (const float*)d_in[12];
    const float* blv = (const float*)d_in[13];

    const int n = in_sizes[0] / 128;   // 100000
    const int e = in_sizes[1] / 2;     // 1600000

    char* ws = (char*)d_ws;
    size_t off = 0;
    auto alloc = [&](size_t bytes) {
        void* p = ws + off;
        off = (off + bytes + 255) & ~(size_t)255;
        return p;
    };
    float*    bufH    = (float*)alloc((size_t)n * 128 * 4);   // fp32 h buffer
    unsigned* hWb     = (unsigned*)alloc((size_t)n * 64 * 4); // bf16x2 hW buffer
    int*      csr_src = (int*)alloc((size_t)e * 4);
    unsigned* deg     = (unsigned*)alloc((size_t)n * 4);
    float*    dis     = (float*)alloc((size_t)n * 4);
    unsigned* starts  = (unsigned*)alloc((size_t)n * 4);
    unsigned* cursor  = (unsigned*)alloc((size_t)n * 4);
    unsigned* total   = (unsigned*)alloc(256);
    int*      eflag   = (int*)alloc(256);
    float*    sums    = (float*)alloc(256 * 4);
    float*    bnp     = (float*)alloc(256 * 4);
    float*    Wcat    = (float*)alloc(16384 * 4);
    float*    bcat    = (float*)alloc(128 * 4);
    // ws total ~85 MB (<=103 MB verified available)

    const int eb = (e + 255) / 256;
    const int nb = (n + 255) / 256;
    const int ab = (n + 3) / 4;
    const int gg = (n + 63) / 64;

    // graph preprocessing (CSR by dst)
    hipMemsetAsync(deg, 0, (size_t)n * 4, stream);
    hipMemsetAsync(total, 0, 4, stream);
    k_edetect<<<1, 64, 0, stream>>>(ei, n, eflag);
    deg_count<<<eb, 256, 0, stream>>>(ei, eflag, deg, e, n);
    node_init<<<nb, 256, 0, stream>>>(deg, dis, starts, cursor, total, n);
    csr_fill<<<eb, 256, 0, stream>>>(ei, eflag, cursor, csr_src, e, n);

    // layer 1: hW1 = x@W1 -> hWb (bf16) ; h1 = agg+b1 -> bufH ; bn1
    gemm64<false><<<gg, 256, 0, stream>>>(x, W1, nullptr, nullptr, hWb, n);
    aggregate<<<ab, 256, 0, stream>>>(hWb, csr_src, starts, deg, dis, b1, bufH, n);
    hipMemsetAsync(sums, 0, 1024, stream);
    bn_stats<<<512, 256, 0, stream>>>(bufH, sums, n);
    bn_final<<<1, 128, 0, stream>>>(sums, g1, be1, bnp, n);

    // layer 2: hW2 = bnrelu(h1)@W2 -> hWb ; h2 = agg+b2 -> bufH ; bn2
    gemm64<false><<<gg, 256, 0, stream>>>(bufH, W2, bnp, nullptr, hWb, n);
    aggregate<<<ab, 256, 0, stream>>>(hWb, csr_src, starts, deg, dis, b2, bufH, n);
    hipMemsetAsync(sums, 0, 1024, stream);
    bn_stats<<<512, 256, 0, stream>>>(bufH, sums, n);
    bn_final<<<1, 128, 0, stream>>>(sums, g2, be2, bnp, n);

    // heads: bnrelu(h2)@[Wmu|Wlv]+[bmu|blv] -> d_out (mu||lv) directly
    pack_head<<<64, 256, 0, stream>>>(Wmu, Wlv, bmu, blv, Wcat, bcat);
    gemm64<true><<<gg, 256, 0, stream>>>(bufH, Wcat, bnp, bcat, d_out, n);
}

// Round 14
// 612.855 us; speedup vs baseline: 21.0375x; 1.2849x over previous
//
#include <hip/hip_runtime.h>

// ---------------------------------------------------------------------------
// StructureEncoder — CSR gather aggregation over bf16 hW with ILP-4 unroll
// (round-13 profile: latency-bound, not BW-bound), 64x128-tile fp32 GEMM
// (4x8 micro-tile, conflict-free column-pair mapping), BN+ReLU fused into
// GEMM A-load, head GEMM writes d_out directly.
// ---------------------------------------------------------------------------

__device__ inline unsigned short f2bf(float f) {
    unsigned u = __float_as_uint(f);
    unsigned r = u + 0x7FFFu + ((u >> 16) & 1u);   // RNE
    return (unsigned short)(r >> 16);
}
__device__ inline float bf2f(unsigned u16) {
    return __uint_as_float(u16 << 16);
}

__global__ void k_edetect(const int* __restrict__ ei, int n, int* __restrict__ flag) {
    if (threadIdx.x == 0 && blockIdx.x == 0) {
        int is64 = 1;
        for (int i = 0; i < 64; ++i) {
            if (ei[2 * i + 1] != 0 || (unsigned)ei[2 * i] >= (unsigned)n) { is64 = 0; break; }
        }
        *flag = is64;
    }
}

__global__ __launch_bounds__(256) void deg_count(const int* __restrict__ ei,
                                                 const int* __restrict__ eflag,
                                                 unsigned* __restrict__ deg, int e, int n) {
    int i = blockIdx.x * 256 + threadIdx.x;
    if (i >= e) return;
    int d = (*eflag) ? ei[2 * (size_t)e + 2 * (size_t)i] : ei[(size_t)e + i];
    if ((unsigned)d < (unsigned)n) atomicAdd(&deg[d], 1u);
}

__global__ __launch_bounds__(256) void node_init(const unsigned* __restrict__ deg,
                                                 float* __restrict__ dis,
                                                 unsigned* __restrict__ starts,
                                                 unsigned* __restrict__ cursor,
                                                 unsigned* __restrict__ total, int n) {
    int i = blockIdx.x * 256 + threadIdx.x;
    if (i < n) {
        unsigned d = deg[i];
        dis[i] = rsqrtf((float)d + 1.0f);          // degree with self loop
        unsigned s = atomicAdd(total, d);
        starts[i] = s;
        cursor[i] = s;
    }
}

__global__ __launch_bounds__(256) void csr_fill(const int* __restrict__ ei,
                                                const int* __restrict__ eflag,
                                                unsigned* __restrict__ cursor,
                                                int* __restrict__ csr_src, int e, int n) {
    int i = blockIdx.x * 256 + threadIdx.x;
    if (i >= e) return;
    int s, d;
    if (*eflag) {
        s = ei[2 * (size_t)i];
        d = ei[2 * (size_t)e + 2 * (size_t)i];
    } else {
        s = ei[i];
        d = ei[(size_t)e + i];
    }
    if ((unsigned)s >= (unsigned)n || (unsigned)d >= (unsigned)n) return;
    unsigned slot = atomicAdd(&cursor[d], 1u);
    if (slot < (unsigned)e) csr_src[slot] = s;
}

// ---- aggregation (gather, bf16 hW, ILP-4): one 64-lane wave per node -------
// out[node] = dis[node]*sum_e dis[src]*hW[src] + dis[node]^2*hW[node] + bias

__global__ __launch_bounds__(256) void aggregate(const unsigned* __restrict__ hWb,  // bf16x2
                                                 const int* __restrict__ csr_src,
                                                 const unsigned* __restrict__ starts,
                                                 const unsigned* __restrict__ deg,
                                                 const float* __restrict__ dis,
                                                 const float* __restrict__ bias,
                                                 float* __restrict__ outh, int n) {
    int node = blockIdx.x * 4 + (threadIdx.x >> 6);
    int lane = threadIdx.x & 63;
    if (node >= n) return;
    unsigned s0 = starts[node], dn = deg[node];
    float ax = 0.f, ay = 0.f;
    unsigned j = 0;
    // ILP-4: 4 independent row gathers in flight per iteration
    for (; j + 4 <= dn; j += 4) {
        int ia = csr_src[s0 + j + 0];
        int ib = csr_src[s0 + j + 1];
        int ic = csr_src[s0 + j + 2];
        int id = csr_src[s0 + j + 3];
        unsigned va = hWb[(size_t)ia * 64 + lane];
        unsigned vb = hWb[(size_t)ib * 64 + lane];
        unsigned vc = hWb[(size_t)ic * 64 + lane];
        unsigned vd = hWb[(size_t)id * 64 + lane];
        float wa = dis[ia], wb = dis[ib], wc = dis[ic], wd = dis[id];
        ax = fmaf(bf2f(va & 0xFFFFu), wa, ax);
        ay = fmaf(bf2f(va >> 16), wa, ay);
        ax = fmaf(bf2f(vb & 0xFFFFu), wb, ax);
        ay = fmaf(bf2f(vb >> 16), wb, ay);
        ax = fmaf(bf2f(vc & 0xFFFFu), wc, ax);
        ay = fmaf(bf2f(vc >> 16), wc, ay);
        ax = fmaf(bf2f(vd & 0xFFFFu), wd, ax);
        ay = fmaf(bf2f(vd >> 16), wd, ay);
    }
    for (; j < dn; ++j) {
        int      s = csr_src[s0 + j];
        float    w = dis[s];
        unsigned v = hWb[(size_t)s * 64 + lane];
        ax = fmaf(bf2f(v & 0xFFFFu), w, ax);
        ay = fmaf(bf2f(v >> 16), w, ay);
    }
    float dii = dis[node];
    unsigned vs = hWb[(size_t)node * 64 + lane];
    float rx = fmaf(dii, ax, dii * dii * bf2f(vs & 0xFFFFu)) + bias[lane * 2];
    float ry = fmaf(dii, ay, dii * dii * bf2f(vs >> 16)) + bias[lane * 2 + 1];
    *(float2*)(outh + (size_t)node * 128 + lane * 2) = make_float2(rx, ry);
}

// ---- BatchNorm statistics --------------------------------------------------

__global__ __launch_bounds__(256) void bn_stats(const float* __restrict__ h,
                                                float* __restrict__ sums, int n) {
    int tid = threadIdx.x;
    int c = tid & 127, half = tid >> 7;
    float s = 0.f, s2 = 0.f;
    for (int r = blockIdx.x * 2 + half; r < n; r += gridDim.x * 2) {
        float v = h[(size_t)r * 128 + c];
        s += v;
        s2 = fmaf(v, v, s2);
    }
    __shared__ float sh[256];
    sh[tid] = s;
    __syncthreads();
    if (tid < 128) atomicAdd(&sums[tid], sh[tid] + sh[tid + 128]);
    __syncthreads();
    sh[tid] = s2;
    __syncthreads();
    if (tid < 128) atomicAdd(&sums[128 + tid], sh[tid] + sh[tid + 128]);
}

__global__ void bn_final(const float* __restrict__ sums, const float* __restrict__ g,
                         const float* __restrict__ be, float* __restrict__ bnp, int n) {
    int c = threadIdx.x;                            // 128 threads
    float inv_n = 1.0f / (float)n;
    float mean = sums[c] * inv_n;
    float var  = sums[128 + c] * inv_n - mean * mean;
    float sc   = g[c] * rsqrtf(var + 1e-5f);
    bnp[c]       = sc;
    bnp[128 + c] = be[c] - mean * sc;
}

// ---- head weight packing: Wcat[k][j] = j<64 ? Wmu : Wlv --------------------

__global__ __launch_bounds__(256) void pack_head(const float* __restrict__ Wmu,
                                                 const float* __restrict__ Wlv,
                                                 const float* __restrict__ bmu,
                                                 const float* __restrict__ blv,
                                                 float* __restrict__ Wcat,
                                                 float* __restrict__ bcat) {
    int idx = blockIdx.x * 256 + threadIdx.x;
    if (idx < 16384) {
        int k = idx >> 7, j = idx & 127;
        Wcat[idx] = (j < 64) ? Wmu[k * 64 + j] : Wlv[k * 64 + (j - 64)];
    }
    if (idx < 128) bcat[idx] = (idx < 64) ? bmu[idx] : blv[idx - 64];
}

// ---- tiled fp32 GEMM: C[M,128] = bnrelu(A)[M,128] @ W[128,128] -------------
// 64 rows x 128 cols per 256-thread block, 4x8 micro-tile (32 acc regs).
// Column-pair mapping: thread covers cols {tx*4..+3} and {64+tx*4..+3}
// (16B LDS stride -> 2-way bank aliasing = free). BN+ReLU fused on A load.

template <bool HEAD>
__global__ __launch_bounds__(256, 3) void gemm64(const float* __restrict__ A,
                                                 const float* __restrict__ W,
                                                 const float* __restrict__ bnp,
                                                 const float* __restrict__ bias,
                                                 void* __restrict__ Cv, int nrows) {
    __shared__ float Ast[32][68];    // A^T chunk [k][row]
    __shared__ float Bs[32][132];    // W chunk [k][col] full 128 width
    __shared__ float bnsc[128], bnsh[128];

    const int tid = threadIdx.x;
    const int rowbase = blockIdx.x * 64;
    const bool has_bn = (bnp != nullptr);
    if (has_bn && tid < 128) {
        bnsc[tid] = bnp[tid];
        bnsh[tid] = bnp[128 + tid];
    }
    __syncthreads();

    const int tx = tid & 15, ty = tid >> 4;
    float acc[4][8];
#pragma unroll
    for (int i = 0; i < 4; ++i)
#pragma unroll
        for (int j = 0; j < 8; ++j) acc[i][j] = 0.f;

    for (int k0 = 0; k0 < 128; k0 += 32) {
        // stage A tile (64 rows x 32 k), transposed, BN+ReLU fused
#pragma unroll
        for (int p = 0; p < 2; ++p) {
            int idx = tid + p * 256;
            int r   = idx >> 3;
            int kc  = (idx & 7) * 4;
            int gr  = rowbase + r;
            float4 v = make_float4(0.f, 0.f, 0.f, 0.f);
            if (gr < nrows) v = *(const float4*)(A + (size_t)gr * 128 + k0 + kc);
            if (has_bn) {
                v.x = fmaxf(0.f, fmaf(v.x, bnsc[k0 + kc + 0], bnsh[k0 + kc + 0]));
                v.y = fmaxf(0.f, fmaf(v.y, bnsc[k0 + kc + 1], bnsh[k0 + kc + 1]));
                v.z = fmaxf(0.f, fmaf(v.z, bnsc[k0 + kc + 2], bnsh[k0 + kc + 2]));
                v.w = fmaxf(0.f, fmaf(v.w, bnsc[k0 + kc + 3], bnsh[k0 + kc + 3]));
            }
            Ast[kc + 0][r] = v.x;
            Ast[kc + 1][r] = v.y;
            Ast[kc + 2][r] = v.z;
            Ast[kc + 3][r] = v.w;
        }
        // stage W tile (32 k x 128 cols)
#pragma unroll
        for (int p = 0; p < 4; ++p) {
            int idx = tid + p * 256;
            int kr  = idx >> 5;
            int c4  = (idx & 31) * 4;
            *(float4*)&Bs[kr][c4] = *(const float4*)(W + (size_t)(k0 + kr) * 128 + c4);
        }
        __syncthreads();

#pragma unroll
        for (int kk = 0; kk < 32; ++kk) {
            float4 a  = *(const float4*)&Ast[kk][ty * 4];
            float4 b0 = *(const float4*)&Bs[kk][tx * 4];
            float4 b1 = *(const float4*)&Bs[kk][64 + tx * 4];
            float av[4] = {a.x, a.y, a.z, a.w};
            float bv[8] = {b0.x, b0.y, b0.z, b0.w, b1.x, b1.y, b1.z, b1.w};
#pragma unroll
            for (int i = 0; i < 4; ++i)
#pragma unroll
                for (int j = 0; j < 8; ++j)
                    acc[i][j] = fmaf(av[i], bv[j], acc[i][j]);
        }
        __syncthreads();
    }

    if (!HEAD) {
        // bf16-packed store: cols tx*4..+3 and 64+tx*4..+3 (2x uint2 = 8B each)
        unsigned* C = (unsigned*)Cv;
#pragma unroll
        for (int i = 0; i < 4; ++i) {
            int r = rowbase + ty * 4 + i;
            if (r < nrows) {
                uint2 o0, o1;
                o0.x = (unsigned)f2bf(acc[i][0]) | ((unsigned)f2bf(acc[i][1]) << 16);
                o0.y = (unsigned)f2bf(acc[i][2]) | ((unsigned)f2bf(acc[i][3]) << 16);
                o1.x = (unsigned)f2bf(acc[i][4]) | ((unsigned)f2bf(acc[i][5]) << 16);
                o1.y = (unsigned)f2bf(acc[i][6]) | ((unsigned)f2bf(acc[i][7]) << 16);
                *(uint2*)(C + (size_t)r * 64 + tx * 2) = o0;
                *(uint2*)(C + (size_t)r * 64 + 32 + tx * 2) = o1;
            }
        }
    } else {
        // fp32 split store: acc[.][0..3] -> mu col tx*4, acc[.][4..7] -> lv col tx*4
        float* mu = (float*)Cv;
        float* lv = mu + (size_t)nrows * 64;
        float4 bb0 = *(const float4*)&bias[tx * 4];
        float4 bb1 = *(const float4*)&bias[64 + tx * 4];
#pragma unroll
        for (int i = 0; i < 4; ++i) {
            int r = rowbase + ty * 4 + i;
            if (r < nrows) {
                *(float4*)(mu + (size_t)r * 64 + tx * 4) =
                    make_float4(acc[i][0] + bb0.x, acc[i][1] + bb0.y,
                                acc[i][2] + bb0.z, acc[i][3] + bb0.w);
                *(float4*)(lv + (size_t)r * 64 + tx * 4) =
                    make_float4(acc[i][4] + bb1.x, acc[i][5] + bb1.y,
                                acc[i][6] + bb1.z, acc[i][7] + bb1.w);
            }
        }
    }
}

// ---------------------------------------------------------------------------

extern "C" void kernel_launch(void* const* d_in, const int* in_sizes, int n_in,
                              void* d_out, int out_size, void* d_ws, size_t ws_size,
                              hipStream_t stream) {
    const float* x   = (const float*)d_in[0];
    const int*   ei  = (const int*)d_in[1];
    const float* W1  = (const float*)d_in[2];
    const float* b1  = (const float*)d_in[3];
    const float* g1  = (const float*)d_in[4];
    const float* be1 = (const float*)d_in[5];
    const float* W2  = (const float*)d_in[6];
    const float* b2  = (const float*)d_in[7];
    const float* g2  = (const float*)d_in[8];
    const float* be2 = (const float*)d_in[9];
    const float* Wmu = (const float*)d_in[10];
    const float* bmu = (const float*)d_in[11];
    const float* Wlv = (const float*)d_in[12];
    const float* blv = (const float*)d_in[13];

    const int n = in_sizes[0] / 128;   // 100000
    const int e = in_sizes[1] / 2;     // 1600000

    char* ws = (char*)d_ws;
    size_t off = 0;
    auto alloc = [&](size_t bytes) {
        void* p = ws + off;
        off = (off + bytes + 255) & ~(size_t)255;
        return p;
    };
    float*    bufH    = (float*)alloc((size_t)n * 128 * 4);   // fp32 h buffer
    unsigned* hWb     = (unsigned*)alloc((size_t)n * 64 * 4); // bf16x2 hW buffer
    int*      csr_src = (int*)alloc((size_t)e * 4);
    unsigned* deg     = (unsigned*)alloc((size_t)n * 4);
    float*    dis     = (float*)alloc((size_t)n * 4);
    unsigned* starts  = (unsigned*)alloc((size_t)n * 4);
    unsigned* cursor  = (unsigned*)alloc((size_t)n * 4);
    unsigned* total   = (unsigned*)alloc(256);
    int*      eflag   = (int*)alloc(256);
    float*    sums    = (float*)alloc(256 * 4);
    float*    bnp     = (float*)alloc(256 * 4);
    float*    Wcat    = (float*)alloc(16384 * 4);
    float*    bcat    = (float*)alloc(128 * 4);

    const int eb = (e + 255) / 256;
    const int nb = (n + 255) / 256;
    const int ab = (n + 3) / 4;
    const int gg = (n + 63) / 64;

    // graph preprocessing (CSR by dst)
    hipMemsetAsync(deg, 0, (size_t)n * 4, stream);
    hipMemsetAsync(total, 0, 4, stream);
    k_edetect<<<1, 64, 0, stream>>>(ei, n, eflag);
    deg_count<<<eb, 256, 0, stream>>>(ei, eflag, deg, e, n);
    node_init<<<nb, 256, 0, stream>>>(deg, dis, starts, cursor, total, n);
    csr_fill<<<eb, 256, 0, stream>>>(ei, eflag, cursor, csr_src, e, n);

    // layer 1: hW1 = x@W1 -> hWb (bf16) ; h1 = agg+b1 -> bufH ; bn1
    gemm64<false><<<gg, 256, 0, stream>>>(x, W1, nullptr, nullptr, hWb, n);
    aggregate<<<ab, 256, 0, stream>>>(hWb, csr_src, starts, deg, dis, b1, bufH, n);
    hipMemsetAsync(sums, 0, 1024, stream);
    bn_stats<<<512, 256, 0, stream>>>(bufH, sums, n);
    bn_final<<<1, 128, 0, stream>>>(sums, g1, be1, bnp, n);

    // layer 2: hW2 = bnrelu(h1)@W2 -> hWb ; h2 = agg+b2 -> bufH ; bn2
    gemm64<false><<<gg, 256, 0, stream>>>(bufH, W2, bnp, nullptr, hWb, n);
    aggregate<<<ab, 256, 0, stream>>>(hWb, csr_src, starts, deg, dis, b2, bufH, n);
    hipMemsetAsync(sums, 0, 1024, stream);
    bn_stats<<<512, 256, 0, stream>>>(bufH, sums, n);
    bn_final<<<1, 128, 0, stream>>>(sums, g2, be2, bnp, n);

    // heads: bnrelu(h2)@[Wmu|Wlv]+[bmu|blv] -> d_out (mu||lv) directly
    pack_head<<<64, 256, 0, stream>>>(Wmu, Wlv, bmu, blv, Wcat, bcat);
    gemm64<true><<<gg, 256, 0, stream>>>(bufH, Wcat, bnp, bcat, d_out, n);
}

// Round 15
// 572.273 us; speedup vs baseline: 22.5294x; 1.0709x over previous
//
#include <hip/hip_runtime.h>

// ---------------------------------------------------------------------------
// StructureEncoder — MFMA bf16 GEMMs (16x16x32, W pre-transposed to bf16),
// CSR gather aggregation (bf16 payload, ILP-8), BN+ReLU fused into GEMM
// A-load, head GEMM writes d_out directly.
// ---------------------------------------------------------------------------

typedef __attribute__((ext_vector_type(8))) short bf16x8;
typedef __attribute__((ext_vector_type(4))) float f32x4;

__device__ inline unsigned short f2bf(float f) {
    unsigned u = __float_as_uint(f);
    unsigned r = u + 0x7FFFu + ((u >> 16) & 1u);   // RNE
    return (unsigned short)(r >> 16);
}
__device__ inline float bf2f(unsigned u16) {
    return __uint_as_float(u16 << 16);
}

__global__ void k_edetect(const int* __restrict__ ei, int n, int* __restrict__ flag) {
    if (threadIdx.x == 0 && blockIdx.x == 0) {
        int is64 = 1;
        for (int i = 0; i < 64; ++i) {
            if (ei[2 * i + 1] != 0 || (unsigned)ei[2 * i] >= (unsigned)n) { is64 = 0; break; }
        }
        *flag = is64;
    }
}

__global__ __launch_bounds__(256) void deg_count(const int* __restrict__ ei,
                                                 const int* __restrict__ eflag,
                                                 unsigned* __restrict__ deg, int e, int n) {
    int i = blockIdx.x * 256 + threadIdx.x;
    if (i >= e) return;
    int d = (*eflag) ? ei[2 * (size_t)e + 2 * (size_t)i] : ei[(size_t)e + i];
    if ((unsigned)d < (unsigned)n) atomicAdd(&deg[d], 1u);
}

__global__ __launch_bounds__(256) void node_init(const unsigned* __restrict__ deg,
                                                 float* __restrict__ dis,
                                                 unsigned* __restrict__ starts,
                                                 unsigned* __restrict__ cursor,
                                                 unsigned* __restrict__ total, int n) {
    int i = blockIdx.x * 256 + threadIdx.x;
    if (i < n) {
        unsigned d = deg[i];
        dis[i] = rsqrtf((float)d + 1.0f);          // degree with self loop
        unsigned s = atomicAdd(total, d);
        starts[i] = s;
        cursor[i] = s;
    }
}

__global__ __launch_bounds__(256) void csr_fill(const int* __restrict__ ei,
                                                const int* __restrict__ eflag,
                                                unsigned* __restrict__ cursor,
                                                int* __restrict__ csr_src, int e, int n) {
    int i = blockIdx.x * 256 + threadIdx.x;
    if (i >= e) return;
    int s, d;
    if (*eflag) {
        s = ei[2 * (size_t)i];
        d = ei[2 * (size_t)e + 2 * (size_t)i];
    } else {
        s = ei[i];
        d = ei[(size_t)e + i];
    }
    if ((unsigned)s >= (unsigned)n || (unsigned)d >= (unsigned)n) return;
    unsigned slot = atomicAdd(&cursor[d], 1u);
    if (slot < (unsigned)e) csr_src[slot] = s;
}

// ---- weight prep: Wt[c][k] = bf16(W[k][c]) for W1, W2, [Wmu|Wlv]; bcat -----

__global__ __launch_bounds__(256) void prep_weights(const float* __restrict__ W1,
                                                    const float* __restrict__ W2,
                                                    const float* __restrict__ Wmu,
                                                    const float* __restrict__ Wlv,
                                                    const float* __restrict__ bmu,
                                                    const float* __restrict__ blv,
                                                    unsigned short* __restrict__ Wt1,
                                                    unsigned short* __restrict__ Wt2,
                                                    unsigned short* __restrict__ Wtc,
                                                    float* __restrict__ bcat) {
    int idx = blockIdx.x * 256 + threadIdx.x;
    if (idx < 16384) {
        int c = idx >> 7, k = idx & 127;
        Wt1[idx] = f2bf(W1[(size_t)k * 128 + c]);
    } else if (idx < 32768) {
        int t = idx - 16384, c = t >> 7, k = t & 127;
        Wt2[t] = f2bf(W2[(size_t)k * 128 + c]);
    } else if (idx < 49152) {
        int t = idx - 32768, c = t >> 7, k = t & 127;
        float v = (c < 64) ? Wmu[(size_t)k * 64 + c] : Wlv[(size_t)k * 64 + (c - 64)];
        Wtc[t] = f2bf(v);
    }
    if (idx < 128) bcat[idx] = (idx < 64) ? bmu[idx] : blv[idx - 64];
}

// ---- aggregation (gather, bf16 hW, ILP-8/4): one 64-lane wave per node -----

__global__ __launch_bounds__(256) void aggregate(const unsigned* __restrict__ hWb,  // bf16x2
                                                 const int* __restrict__ csr_src,
                                                 const unsigned* __restrict__ starts,
                                                 const unsigned* __restrict__ deg,
                                                 const float* __restrict__ dis,
                                                 const float* __restrict__ bias,
                                                 float* __restrict__ outh, int n) {
    int node = blockIdx.x * 4 + (threadIdx.x >> 6);
    int lane = threadIdx.x & 63;
    if (node >= n) return;
    unsigned s0 = starts[node], dn = deg[node];
    float ax = 0.f, ay = 0.f;
    unsigned j = 0;
    for (; j + 8 <= dn; j += 8) {
        int si[8]; unsigned vv[8]; float ww[8];
#pragma unroll
        for (int q = 0; q < 8; ++q) si[q] = csr_src[s0 + j + q];
#pragma unroll
        for (int q = 0; q < 8; ++q) vv[q] = hWb[(size_t)si[q] * 64 + lane];
#pragma unroll
        for (int q = 0; q < 8; ++q) ww[q] = dis[si[q]];
#pragma unroll
        for (int q = 0; q < 8; ++q) {
            ax = fmaf(bf2f(vv[q] & 0xFFFFu), ww[q], ax);
            ay = fmaf(bf2f(vv[q] >> 16), ww[q], ay);
        }
    }
    for (; j + 4 <= dn; j += 4) {
        int si[4]; unsigned vv[4]; float ww[4];
#pragma unroll
        for (int q = 0; q < 4; ++q) si[q] = csr_src[s0 + j + q];
#pragma unroll
        for (int q = 0; q < 4; ++q) vv[q] = hWb[(size_t)si[q] * 64 + lane];
#pragma unroll
        for (int q = 0; q < 4; ++q) ww[q] = dis[si[q]];
#pragma unroll
        for (int q = 0; q < 4; ++q) {
            ax = fmaf(bf2f(vv[q] & 0xFFFFu), ww[q], ax);
            ay = fmaf(bf2f(vv[q] >> 16), ww[q], ay);
        }
    }
    for (; j < dn; ++j) {
        int      s = csr_src[s0 + j];
        float    w = dis[s];
        unsigned v = hWb[(size_t)s * 64 + lane];
        ax = fmaf(bf2f(v & 0xFFFFu), w, ax);
        ay = fmaf(bf2f(v >> 16), w, ay);
    }
    float dii = dis[node];
    unsigned vs = hWb[(size_t)node * 64 + lane];
    float rx = fmaf(dii, ax, dii * dii * bf2f(vs & 0xFFFFu)) + bias[lane * 2];
    float ry = fmaf(dii, ay, dii * dii * bf2f(vs >> 16)) + bias[lane * 2 + 1];
    *(float2*)(outh + (size_t)node * 128 + lane * 2) = make_float2(rx, ry);
}

// ---- BatchNorm statistics --------------------------------------------------

__global__ __launch_bounds__(256) void bn_stats(const float* __restrict__ h,
                                                float* __restrict__ sums, int n) {
    int tid = threadIdx.x;
    int c = tid & 127, half = tid >> 7;
    float s = 0.f, s2 = 0.f;
    for (int r = blockIdx.x * 2 + half; r < n; r += gridDim.x * 2) {
        float v = h[(size_t)r * 128 + c];
        s += v;
        s2 = fmaf(v, v, s2);
    }
    __shared__ float sh[256];
    sh[tid] = s;
    __syncthreads();
    if (tid < 128) atomicAdd(&sums[tid], sh[tid] + sh[tid + 128]);
    __syncthreads();
    sh[tid] = s2;
    __syncthreads();
    if (tid < 128) atomicAdd(&sums[128 + tid], sh[tid] + sh[tid + 128]);
}

__global__ void bn_final(const float* __restrict__ sums, const float* __restrict__ g,
                         const float* __restrict__ be, float* __restrict__ bnp, int n) {
    int c = threadIdx.x;                            // 128 threads
    float inv_n = 1.0f / (float)n;
    float mean = sums[c] * inv_n;
    float var  = sums[128 + c] * inv_n - mean * mean;
    float sc   = g[c] * rsqrtf(var + 1e-5f);
    bnp[c]       = sc;
    bnp[128 + c] = be[c] - mean * sc;
}

// ---- MFMA GEMM: C[M,128] = bnrelu(A)[M,128] @ W[128,128] -------------------
// Block: 256 thr = 4 waves; 64 rows x 128 cols. Wave w: rows w*16..+15,
// 8 col-tiles x 4 K-chunks of mfma_f32_16x16x32_bf16 (acc = 8 x f32x4).
// A frag: lane l -> row (l&15), k = kchunk + (l>>4)*8 + i (fp32 load, BN+ReLU,
// cvt bf16). B frag: lane l -> col (l&15) of tile, same k (16B load from
// pre-transposed bf16 Wt[c][k]). C/D: col=lane&15, row=(lane>>4)*4+reg.
// Epilogue via LDS for coalesced stores: bf16-packed hW or fp32 mu|lv+bias.

template <bool HEAD>
__global__ __launch_bounds__(256, 4) void gemm_mfma(const float* __restrict__ A,
                                                    const unsigned short* __restrict__ Wt,
                                                    const float* __restrict__ bnp,
                                                    const float* __restrict__ bias,
                                                    void* __restrict__ Cv, int nrows) {
    __shared__ float Cl[64][130];
    __shared__ float bnsc[128], bnsh[128];

    const int tid  = threadIdx.x;
    const int lane = tid & 63;
    const int wv   = tid >> 6;
    const int rowbase = blockIdx.x * 64;
    const bool has_bn = (bnp != nullptr);
    if (has_bn && tid < 128) {
        bnsc[tid] = bnp[tid];
        bnsh[tid] = bnp[128 + tid];
    }
    __syncthreads();

    const int ar = rowbase + wv * 16 + (lane & 15);   // global A row for this lane
    const int kg = (lane >> 4) * 8;                   // k sub-offset
    const int bc = lane & 15;                         // B col within tile

    f32x4 acc[8];
#pragma unroll
    for (int t = 0; t < 8; ++t) acc[t] = {0.f, 0.f, 0.f, 0.f};

#pragma unroll
    for (int k0 = 0; k0 < 128; k0 += 32) {
        float va[8];
        if (ar < nrows) {
            float4 a0 = *(const float4*)(A + (size_t)ar * 128 + k0 + kg);
            float4 a1 = *(const float4*)(A + (size_t)ar * 128 + k0 + kg + 4);
            va[0] = a0.x; va[1] = a0.y; va[2] = a0.z; va[3] = a0.w;
            va[4] = a1.x; va[5] = a1.y; va[6] = a1.z; va[7] = a1.w;
        } else {
#pragma unroll
            for (int i = 0; i < 8; ++i) va[i] = 0.f;
        }
        if (has_bn) {
#pragma unroll
            for (int i = 0; i < 8; ++i) {
                int k = k0 + kg + i;
                va[i] = fmaxf(0.f, fmaf(va[i], bnsc[k], bnsh[k]));
            }
        }
        bf16x8 af;
#pragma unroll
        for (int i = 0; i < 8; ++i) af[i] = (short)f2bf(va[i]);

#pragma unroll
        for (int ct = 0; ct < 8; ++ct) {
            bf16x8 bf = *(const bf16x8*)(Wt + (size_t)(ct * 16 + bc) * 128 + k0 + kg);
            acc[ct] = __builtin_amdgcn_mfma_f32_16x16x32_bf16(af, bf, acc[ct], 0, 0, 0);
        }
    }

    // scatter accumulators to LDS (verified C/D layout), then coalesced store
    const int lr = wv * 16 + ((lane >> 4) << 2);
#pragma unroll
    for (int ct = 0; ct < 8; ++ct)
#pragma unroll
        for (int r = 0; r < 4; ++r)
            Cl[lr + r][ct * 16 + bc] = acc[ct][r];
    __syncthreads();

    const int row = tid >> 2;            // 0..63
    const int c0  = (tid & 3) * 32;      // 32-col span per thread
    const int gr  = rowbase + row;
    if (gr < nrows) {
        if (!HEAD) {
            unsigned* C = (unsigned*)Cv;  // bf16x2 words, 64/row
#pragma unroll
            for (int u = 0; u < 4; ++u) {
                int cb = c0 + u * 8;
                uint2 o;
                o.x = (unsigned)f2bf(Cl[row][cb + 0]) | ((unsigned)f2bf(Cl[row][cb + 1]) << 16);
                o.y = (unsigned)f2bf(Cl[row][cb + 2]) | ((unsigned)f2bf(Cl[row][cb + 3]) << 16);
                unsigned o2x = (unsigned)f2bf(Cl[row][cb + 4]) | ((unsigned)f2bf(Cl[row][cb + 5]) << 16);
                unsigned o2y = (unsigned)f2bf(Cl[row][cb + 6]) | ((unsigned)f2bf(Cl[row][cb + 7]) << 16);
                uint4 o4 = {o.x, o.y, o2x, o2y};
                *(uint4*)(C + (size_t)gr * 64 + cb / 2) = o4;
            }
        } else {
            float* mu = (float*)Cv;
            float* lv = mu + (size_t)nrows * 64;
            float* dst = (c0 < 64) ? (mu + (size_t)gr * 64 + c0) : (lv + (size_t)gr * 64 + (c0 - 64));
#pragma unroll
            for (int u = 0; u < 8; ++u) {
                int cb = c0 + u * 4;
                float4 o = make_float4(Cl[row][cb + 0] + bias[cb + 0],
                                       Cl[row][cb + 1] + bias[cb + 1],
                                       Cl[row][cb + 2] + bias[cb + 2],
                                       Cl[row][cb + 3] + bias[cb + 3]);
                *(float4*)(dst + u * 4) = o;
            }
        }
    }
}

// ---------------------------------------------------------------------------

extern "C" void kernel_launch(void* const* d_in, const int* in_sizes, int n_in,
                              void* d_out, int out_size, void* d_ws, size_t ws_size,
                              hipStream_t stream) {
    const float* x   = (const float*)d_in[0];
    const int*   ei  = (const int*)d_in[1];
    const float* W1  = (const float*)d_in[2];
    const float* b1  = (const float*)d_in[3];
    const float* g1  = (const float*)d_in[4];
    const float* be1 = (const float*)d_in[5];
    const float* W2  = (const float*)d_in[6];
    const float* b2  = (const float*)d_in[7];
    const float* g2  = (const float*)d_in[8];
    const float* be2 = (const float*)d_in[9];
    const float* Wmu = (const float*)d_in[10];
    const float* bmu = (const float*)d_in[11];
    const float* Wlv = (const float*)d_in[12];
    const float* blv = (const float*)d_in[13];

    const int n = in_sizes[0] / 128;   // 100000
    const int e = in_sizes[1] / 2;     // 1600000

    char* ws = (char*)d_ws;
    size_t off = 0;
    auto alloc = [&](size_t bytes) {
        void* p = ws + off;
        off = (off + bytes + 255) & ~(size_t)255;
        return p;
    };
    float*          bufH    = (float*)alloc((size_t)n * 128 * 4);
    unsigned*       hWb     = (unsigned*)alloc((size_t)n * 64 * 4);
    int*            csr_src = (int*)alloc((size_t)e * 4);
    unsigned*       deg     = (unsigned*)alloc((size_t)n * 4);
    float*          dis     = (float*)alloc((size_t)n * 4);
    unsigned*       starts  = (unsigned*)alloc((size_t)n * 4);
    unsigned*       cursor  = (unsigned*)alloc((size_t)n * 4);
    unsigned*       total   = (unsigned*)alloc(256);
    int*            eflag   = (int*)alloc(256);
    float*          sums    = (float*)alloc(256 * 4);
    float*          bnp     = (float*)alloc(256 * 4);
    unsigned short* Wt1     = (unsigned short*)alloc(16384 * 2);
    unsigned short* Wt2     = (unsigned short*)alloc(16384 * 2);
    unsigned short* Wtc     = (unsigned short*)alloc(16384 * 2);
    float*          bcat    = (float*)alloc(128 * 4);

    const int eb = (e + 255) / 256;
    const int nb = (n + 255) / 256;
    const int ab = (n + 3) / 4;
    const int gg = (n + 63) / 64;

    // prep: weights transpose+bf16, graph CSR
    hipMemsetAsync(deg, 0, (size_t)n * 4, stream);
    hipMemsetAsync(total, 0, 4, stream);
    prep_weights<<<192, 256, 0, stream>>>(W1, W2, Wmu, Wlv, bmu, blv, Wt1, Wt2, Wtc, bcat);
    k_edetect<<<1, 64, 0, stream>>>(ei, n, eflag);
    deg_count<<<eb, 256, 0, stream>>>(ei, eflag, deg, e, n);
    node_init<<<nb, 256, 0, stream>>>(deg, dis, starts, cursor, total, n);
    csr_fill<<<eb, 256, 0, stream>>>(ei, eflag, cursor, csr_src, e, n);

    // layer 1: hW1 = x@W1 -> hWb (bf16) ; h1 = agg+b1 -> bufH ; bn1
    gemm_mfma<false><<<gg, 256, 0, stream>>>(x, Wt1, nullptr, nullptr, hWb, n);
    aggregate<<<ab, 256, 0, stream>>>(hWb, csr_src, starts, deg, dis, b1, bufH, n);
    hipMemsetAsync(sums, 0, 1024, stream);
    bn_stats<<<512, 256, 0, stream>>>(bufH, sums, n);
    bn_final<<<1, 128, 0, stream>>>(sums, g1, be1, bnp, n);

    // layer 2: hW2 = bnrelu(h1)@W2 -> hWb ; h2 = agg+b2 -> bufH ; bn2
    gemm_mfma<false><<<gg, 256, 0, stream>>>(bufH, Wt2, bnp, nullptr, hWb, n);
    aggregate<<<ab, 256, 0, stream>>>(hWb, csr_src, starts, deg, dis, b2, bufH, n);
    hipMemsetAsync(sums, 0, 1024, stream);
    bn_stats<<<512, 256, 0, stream>>>(bufH, sums, n);
    bn_final<<<1, 128, 0, stream>>>(sums, g2, be2, bnp, n);

    // heads: bnrelu(h2)@[Wmu|Wlv]+[bmu|blv] -> d_out (mu||lv) directly
    gemm_mfma<true><<<gg, 256, 0, stream>>>(bufH, Wtc, bnp, bcat, d_out, n);
}